// Round 1
// baseline (176.227 us; speedup 1.0000x reference)
//
#include <hip/hip_runtime.h>
#include <cstdint>
#include <cstddef>

typedef unsigned short u16;
typedef __attribute__((ext_vector_type(8))) short bf16x8;
typedef __attribute__((ext_vector_type(8))) unsigned short u16x8;
typedef __attribute__((ext_vector_type(4))) float f32x4;

// ---------- helpers ----------
__device__ __forceinline__ u16 f2b(float f) {
    union { float f; uint32_t u; } v; v.f = f;
    uint32_t u = v.u;
    uint32_t r = (u + 0x7FFFu + ((u >> 16) & 1u)) >> 16;
    return (u16)r;
}
__device__ __forceinline__ float b2f(u16 b) {
    union { uint32_t u; float f; } v; v.u = ((uint32_t)b) << 16;
    return v.f;
}
__device__ __forceinline__ void gload_lds16(const void* g, void* l) {
    __builtin_amdgcn_global_load_lds(
        (const __attribute__((address_space(1))) void*)g,
        (__attribute__((address_space(3))) void*)l,
        16, 0, 0);
}

// ---------- f32 -> bf16 elementwise convert (8 elems/thread) ----------
__global__ void cvt_bf16_kernel(const float* __restrict__ in, u16* __restrict__ out, int n8) {
    int i = blockIdx.x * blockDim.x + threadIdx.x;
    if (i >= n8) return;
    const float4* p = (const float4*)(in + (size_t)i * 8);
    float4 a = p[0], b = p[1];
    u16x8 o;
    o[0] = f2b(a.x); o[1] = f2b(a.y); o[2] = f2b(a.z); o[3] = f2b(a.w);
    o[4] = f2b(b.x); o[5] = f2b(b.y); o[6] = f2b(b.z); o[7] = f2b(b.w);
    *(u16x8*)(out + (size_t)i * 8) = o;
}

// ---------- tiled transpose: in[K][N] f32 -> out[N][K] (bf16 or f32) ----------
template <bool TOBF16>
__global__ void transpose_kernel(const float* __restrict__ in, void* __restrict__ outv,
                                 int K, int N) {
    __shared__ float tile[32][33];
    int n0 = blockIdx.x * 32, k0 = blockIdx.y * 32;
    int tx = threadIdx.x & 31, ty = threadIdx.x >> 5;  // 256 thr: ty in [0,8)
#pragma unroll
    for (int r = ty; r < 32; r += 8)
        tile[r][tx] = in[(size_t)(k0 + r) * N + n0 + tx];
    __syncthreads();
#pragma unroll
    for (int r = ty; r < 32; r += 8) {
        float v = tile[tx][r];  // = in[k0+tx][n0+r]
        size_t idx = (size_t)(n0 + r) * K + k0 + tx;
        if (TOBF16) ((u16*)outv)[idx] = f2b(v);
        else        ((float*)outv)[idx] = v;
    }
}

// ---------- bf16 GEMM: C[M,N] = act(A[M,K] @ BT[N,K]^T + bias) ----------
// 128x128 tile, BK=64, 4 waves (2x2), 4x4 16x16x32 MFMA fragments per wave.
template <int RELU>
__global__ __launch_bounds__(256)
void gemm_bt(const u16* __restrict__ A, const u16* __restrict__ BT,
             const float* __restrict__ bias, u16* __restrict__ C,
             int M, int N, int K) {
    __shared__ __align__(16) u16 sA[128 * 64];
    __shared__ __align__(16) u16 sB[128 * 64];
    const int tid = threadIdx.x;
    const int lane = tid & 63;
    const int w = tid >> 6;
    const int wm = w >> 1, wn = w & 1;
    const int lr = lane & 15, lg = lane >> 4;
    const int rowBase = blockIdx.y * 128;
    const int colBase = blockIdx.x * 128;

    f32x4 acc[4][4] = {};

    const int nk = K >> 6;
    const int ci = tid;            // chunk base for staging
    const int srow = ci >> 3;      // j*256 offsets handled in loop
    const int sch = ci & 7;

    for (int kt = 0; kt < nk; ++kt) {
        const int kb = kt << 6;
#pragma unroll
        for (int j = 0; j < 4; ++j) {
            int c = j * 256 + ci;
            int row = c >> 3, ch = c & 7;
            const u16* ga = A + (size_t)(rowBase + row) * K + kb + ch * 8;
            gload_lds16(ga, (char*)sA + (size_t)(j * 256 + (w << 6)) * 16);
            const u16* gb = BT + (size_t)(colBase + row) * K + kb + ch * 8;
            gload_lds16(gb, (char*)sB + (size_t)(j * 256 + (w << 6)) * 16);
        }
        __syncthreads();
#pragma unroll
        for (int kk = 0; kk < 2; ++kk) {
            bf16x8 af[4], bfr[4];
#pragma unroll
            for (int m = 0; m < 4; ++m)
                af[m] = *(const bf16x8*)&sA[(wm * 64 + m * 16 + lr) * 64 + kk * 32 + lg * 8];
#pragma unroll
            for (int n = 0; n < 4; ++n)
                bfr[n] = *(const bf16x8*)&sB[(wn * 64 + n * 16 + lr) * 64 + kk * 32 + lg * 8];
#pragma unroll
            for (int m = 0; m < 4; ++m)
#pragma unroll
                for (int n = 0; n < 4; ++n)
                    acc[m][n] = __builtin_amdgcn_mfma_f32_16x16x32_bf16(
                        af[m], bfr[n], acc[m][n], 0, 0, 0);
        }
        __syncthreads();
    }

    // epilogue: bias (+ relu), store bf16
#pragma unroll
    for (int n = 0; n < 4; ++n) {
        int col = colBase + wn * 64 + n * 16 + lr;
        float bv = bias[col];
#pragma unroll
        for (int m = 0; m < 4; ++m) {
            int row0 = rowBase + wm * 64 + m * 16 + lg * 4;
#pragma unroll
            for (int i = 0; i < 4; ++i) {
                float v = acc[m][n][i] + bv;
                if (RELU) v = v > 0.f ? v : 0.f;
                C[(size_t)(row0 + i) * N + col] = f2b(v);
            }
        }
    }
    (void)srow; (void)sch;
}

// ---------- final: out[n] = sum_k logits[n,k] * wT[n,k] ----------
__global__ void diag_dot(const u16* __restrict__ logits, const float* __restrict__ wT,
                         float* __restrict__ out, int D) {
    int n = blockIdx.x * 4 + (threadIdx.x >> 6);
    int lane = threadIdx.x & 63;
    const u16* lrow = logits + (size_t)n * D + lane * 8;
    const float* wrow = wT + (size_t)n * D + lane * 8;
    u16x8 lv = *(const u16x8*)lrow;
    float4 w0 = *(const float4*)wrow;
    float4 w1 = *(const float4*)(wrow + 4);
    float s = 0.f;
    s += b2f(lv[0]) * w0.x + b2f(lv[1]) * w0.y + b2f(lv[2]) * w0.z + b2f(lv[3]) * w0.w;
    s += b2f(lv[4]) * w1.x + b2f(lv[5]) * w1.y + b2f(lv[6]) * w1.z + b2f(lv[7]) * w1.w;
#pragma unroll
    for (int off = 32; off; off >>= 1) s += __shfl_down(s, off);
    if (lane == 0) out[n] = s;
}

// ---------- launch ----------
extern "C" void kernel_launch(void* const* d_in, const int* in_sizes, int n_in,
                              void* d_out, int out_size, void* d_ws, size_t ws_size,
                              hipStream_t stream) {
    const float* features = (const float*)d_in[0];  // [4096,1024]
    const float* W1 = (const float*)d_in[1];        // [1024,2048]
    const float* b1 = (const float*)d_in[2];
    const float* W2 = (const float*)d_in[3];        // [2048,2048]
    const float* b2 = (const float*)d_in[4];
    const float* W3 = (const float*)d_in[5];        // [2048,1024]
    const float* b3 = (const float*)d_in[6];
    const float* Wh = (const float*)d_in[7];        // [1024,512]
    const float* bh = (const float*)d_in[8];
    const float* w  = (const float*)d_in[9];        // [512,4096]
    float* out = (float*)d_out;

    const int N = 4096, D_in = 1024, H1 = 2048, H2 = 2048, H3 = 1024, D_out = 512;

    // workspace carve-up (aligned 256B)
    size_t off = 0;
    auto alloc = [&](size_t bytes) {
        void* p = (char*)d_ws + off;
        off += (bytes + 255) & ~(size_t)255;
        return p;
    };
    u16* featB = (u16*)alloc((size_t)N * D_in * 2);      // 8MB; reused as h3
    u16* W1T   = (u16*)alloc((size_t)H1 * D_in * 2);     // 4MB; reused as logits
    u16* W2T   = (u16*)alloc((size_t)H2 * H1 * 2);       // 8MB
    u16* W3T   = (u16*)alloc((size_t)H3 * H2 * 2);       // 4MB
    u16* WhT   = (u16*)alloc((size_t)D_out * H3 * 2);    // 1MB
    float* wT  = (float*)alloc((size_t)N * D_out * 4);   // 8MB
    u16* h1    = (u16*)alloc((size_t)N * H1 * 2);        // 16MB
    u16* h2    = (u16*)alloc((size_t)N * H2 * 2);        // 16MB
    u16* h3    = featB;                                  // alias (same size)
    u16* logits = W1T;                                   // alias (same elem count)

    // 1. convert features
    {
        int n8 = N * D_in / 8;
        cvt_bf16_kernel<<<(n8 + 255) / 256, 256, 0, stream>>>(features, featB, n8);
    }
    // 2. transpose+convert weights
    transpose_kernel<true><<<dim3(H1 / 32, D_in / 32), 256, 0, stream>>>(W1, W1T, D_in, H1);
    transpose_kernel<true><<<dim3(H2 / 32, H1 / 32), 256, 0, stream>>>(W2, W2T, H1, H2);
    transpose_kernel<true><<<dim3(H3 / 32, H2 / 32), 256, 0, stream>>>(W3, W3T, H2, H3);
    transpose_kernel<true><<<dim3(D_out / 32, H3 / 32), 256, 0, stream>>>(Wh, WhT, H3, D_out);
    transpose_kernel<false><<<dim3(N / 32, D_out / 32), 256, 0, stream>>>(w, wT, D_out, N);

    // 3. GEMM chain
    gemm_bt<1><<<dim3(H1 / 128, N / 128), 256, 0, stream>>>(featB, W1T, b1, h1, N, H1, D_in);
    gemm_bt<1><<<dim3(H2 / 128, N / 128), 256, 0, stream>>>(h1, W2T, b2, h2, N, H2, H1);
    gemm_bt<0><<<dim3(H3 / 128, N / 128), 256, 0, stream>>>(h2, W3T, b3, h3, N, H3, H2);
    gemm_bt<0><<<dim3(D_out / 128, N / 128), 256, 0, stream>>>(h3, WhT, bh, logits, N, D_out, H3);

    // 4. row-wise dot
    diag_dot<<<N / 4, 256, 0, stream>>>(logits, wT, out, D_out);
}

// Round 2
// 172.681 us; speedup vs baseline: 1.0205x; 1.0205x over previous
//
#include <hip/hip_runtime.h>
#include <cstdint>
#include <cstddef>

typedef unsigned short u16;
typedef __attribute__((ext_vector_type(8))) short bf16x8;
typedef __attribute__((ext_vector_type(8))) unsigned short u16x8;
typedef __attribute__((ext_vector_type(4))) float f32x4;

// ---------- helpers ----------
__device__ __forceinline__ u16 f2b(float f) {
    union { float f; uint32_t u; } v; v.f = f;
    uint32_t u = v.u;
    uint32_t r = (u + 0x7FFFu + ((u >> 16) & 1u)) >> 16;
    return (u16)r;
}
__device__ __forceinline__ void gload_lds16(const void* g, void* l) {
    __builtin_amdgcn_global_load_lds(
        (const __attribute__((address_space(1))) void*)g,
        (__attribute__((address_space(3))) void*)l,
        16, 0, 0);
}

// XCD-aware bijective block swizzle (nwg % 8 == 0 for all our grids).
// Consecutive remapped ids sweep blockIdx.x (col blocks) within one XCD ->
// the shared A row-panel stays hot in that XCD's L2.
__device__ __forceinline__ void xcd_swizzle(int& bx, int& by) {
    int lin = blockIdx.y * gridDim.x + blockIdx.x;
    int nwg = gridDim.x * gridDim.y;
    int u = (lin & 7) * (nwg >> 3) + (lin >> 3);
    bx = u % gridDim.x;
    by = u / gridDim.x;
}

// ---------- merged prep: cvt(features) + 4 weight transposes ----------
// blocks [0,2048): features f32->bf16 (2048 elems/block)
// blocks [2048,4096):  W1 [1024,2048] -> W1T [2048,1024] bf16
// blocks [4096,8192):  W2 [2048,2048] -> W2T
// blocks [8192,10240): W3 [2048,1024] -> W3T [1024,2048]
// blocks [10240,10752): Wh [1024,512] -> WhT [512,1024]
__global__ __launch_bounds__(256) void prep_kernel(
    const float* __restrict__ feat, u16* __restrict__ featB,
    const float* __restrict__ W1, u16* __restrict__ W1T,
    const float* __restrict__ W2, u16* __restrict__ W2T,
    const float* __restrict__ W3, u16* __restrict__ W3T,
    const float* __restrict__ Wh, u16* __restrict__ WhT) {
    __shared__ float tile[32][33];
    const int b = blockIdx.x, tid = threadIdx.x;

    if (b < 2048) {  // features convert, 8 f32 -> 8 bf16 per thread
        size_t base = (size_t)b * 2048 + (size_t)tid * 8;
        const float4* p = (const float4*)(feat + base);
        float4 a = p[0], c = p[1];
        u16x8 o;
        o[0] = f2b(a.x); o[1] = f2b(a.y); o[2] = f2b(a.z); o[3] = f2b(a.w);
        o[4] = f2b(c.x); o[5] = f2b(c.y); o[6] = f2b(c.z); o[7] = f2b(c.w);
        *(u16x8*)(featB + base) = o;
        return;
    }
    const float* in; u16* outp; int K, N, t;
    if (b < 4096)       { t = b - 2048;  in = W1; outp = W1T; K = 1024; N = 2048; }
    else if (b < 8192)  { t = b - 4096;  in = W2; outp = W2T; K = 2048; N = 2048; }
    else if (b < 10240) { t = b - 8192;  in = W3; outp = W3T; K = 2048; N = 1024; }
    else                { t = b - 10240; in = Wh; outp = WhT; K = 1024; N = 512;  }
    const int ntx = N >> 5;
    const int n0 = (t % ntx) * 32, k0 = (t / ntx) * 32;
    const int tx = tid & 31, ty = tid >> 5;
#pragma unroll
    for (int r = ty; r < 32; r += 8)
        tile[r][tx] = in[(size_t)(k0 + r) * N + n0 + tx];
    __syncthreads();
#pragma unroll
    for (int r = ty; r < 32; r += 8)
        outp[(size_t)(n0 + r) * K + k0 + tx] = f2b(tile[tx][r]);
}

// ---------- bf16 GEMM: C[M,N] = act(A[M,K] @ BT[N,K]^T + bias) ----------
// 128x128 tile, BK=64, 4 waves (2x2), 4x4 16x16x32 MFMA fragments per wave.
template <int RELU>
__global__ __launch_bounds__(256)
void gemm_bt(const u16* __restrict__ A, const u16* __restrict__ BT,
             const float* __restrict__ bias, u16* __restrict__ C,
             int M, int N, int K) {
    __shared__ __align__(16) u16 sA[128 * 64];
    __shared__ __align__(16) u16 sB[128 * 64];
    const int tid = threadIdx.x;
    const int lane = tid & 63;
    const int w = tid >> 6;
    const int wm = w >> 1, wn = w & 1;
    const int lr = lane & 15, lg = lane >> 4;
    int bx, by;
    xcd_swizzle(bx, by);
    const int rowBase = by * 128;
    const int colBase = bx * 128;

    f32x4 acc[4][4] = {};
    const int nk = K >> 6;
    const int ci = tid;

    for (int kt = 0; kt < nk; ++kt) {
        const int kb = kt << 6;
#pragma unroll
        for (int j = 0; j < 4; ++j) {
            int c = j * 256 + ci;
            int row = c >> 3, ch = c & 7;
            const u16* ga = A + (size_t)(rowBase + row) * K + kb + ch * 8;
            gload_lds16(ga, (char*)sA + (size_t)(j * 256 + (w << 6)) * 16);
            const u16* gb = BT + (size_t)(colBase + row) * K + kb + ch * 8;
            gload_lds16(gb, (char*)sB + (size_t)(j * 256 + (w << 6)) * 16);
        }
        __syncthreads();
#pragma unroll
        for (int kk = 0; kk < 2; ++kk) {
            bf16x8 af[4], bfr[4];
#pragma unroll
            for (int m = 0; m < 4; ++m)
                af[m] = *(const bf16x8*)&sA[(wm * 64 + m * 16 + lr) * 64 + kk * 32 + lg * 8];
#pragma unroll
            for (int n = 0; n < 4; ++n)
                bfr[n] = *(const bf16x8*)&sB[(wn * 64 + n * 16 + lr) * 64 + kk * 32 + lg * 8];
#pragma unroll
            for (int m = 0; m < 4; ++m)
#pragma unroll
                for (int n = 0; n < 4; ++n)
                    acc[m][n] = __builtin_amdgcn_mfma_f32_16x16x32_bf16(
                        af[m], bfr[n], acc[m][n], 0, 0, 0);
        }
        __syncthreads();
    }

#pragma unroll
    for (int n = 0; n < 4; ++n) {
        int col = colBase + wn * 64 + n * 16 + lr;
        float bv = bias[col];
#pragma unroll
        for (int m = 0; m < 4; ++m) {
            int row0 = rowBase + wm * 64 + m * 16 + lg * 4;
#pragma unroll
            for (int i = 0; i < 4; ++i) {
                float v = acc[m][n][i] + bv;
                if (RELU) v = v > 0.f ? v : 0.f;
                C[(size_t)(row0 + i) * N + col] = f2b(v);
            }
        }
    }
}

// ---------- fused GEMM4 + row-dot ----------
// out[row] += sum_col (A[row,:]@WhT[col,:] + bh[col]) * wmat[col, row]
// Same GEMM body; epilogue multiplies by w[col][row] (stride-M rows of w),
// reduces over the 16 lr-lanes, atomicAdds 64 rows per wave.
__global__ __launch_bounds__(256)
void gemm_dot(const u16* __restrict__ A, const u16* __restrict__ BT,
              const float* __restrict__ bias, const float* __restrict__ wmat,
              float* __restrict__ out, int M, int N, int K) {
    __shared__ __align__(16) u16 sA[128 * 64];
    __shared__ __align__(16) u16 sB[128 * 64];
    const int tid = threadIdx.x;
    const int lane = tid & 63;
    const int wv = tid >> 6;
    const int wm = wv >> 1, wn = wv & 1;
    const int lr = lane & 15, lg = lane >> 4;
    int bx, by;
    xcd_swizzle(bx, by);
    const int rowBase = by * 128;
    const int colBase = bx * 128;

    f32x4 acc[4][4] = {};
    const int nk = K >> 6;
    const int ci = tid;

    for (int kt = 0; kt < nk; ++kt) {
        const int kb = kt << 6;
#pragma unroll
        for (int j = 0; j < 4; ++j) {
            int c = j * 256 + ci;
            int row = c >> 3, ch = c & 7;
            const u16* ga = A + (size_t)(rowBase + row) * K + kb + ch * 8;
            gload_lds16(ga, (char*)sA + (size_t)(j * 256 + (wv << 6)) * 16);
            const u16* gb = BT + (size_t)(colBase + row) * K + kb + ch * 8;
            gload_lds16(gb, (char*)sB + (size_t)(j * 256 + (wv << 6)) * 16);
        }
        __syncthreads();
#pragma unroll
        for (int kk = 0; kk < 2; ++kk) {
            bf16x8 af[4], bfr[4];
#pragma unroll
            for (int m = 0; m < 4; ++m)
                af[m] = *(const bf16x8*)&sA[(wm * 64 + m * 16 + lr) * 64 + kk * 32 + lg * 8];
#pragma unroll
            for (int n = 0; n < 4; ++n)
                bfr[n] = *(const bf16x8*)&sB[(wn * 64 + n * 16 + lr) * 64 + kk * 32 + lg * 8];
#pragma unroll
            for (int m = 0; m < 4; ++m)
#pragma unroll
                for (int n = 0; n < 4; ++n)
                    acc[m][n] = __builtin_amdgcn_mfma_f32_16x16x32_bf16(
                        af[m], bfr[n], acc[m][n], 0, 0, 0);
        }
        __syncthreads();
    }

    // epilogue: logits*w[col][row], reduce over cols
    float psum[4][4] = {};  // [m][i] per-row partials
#pragma unroll
    for (int n = 0; n < 4; ++n) {
        int col = colBase + wn * 64 + n * 16 + lr;
        float bv = bias[col];
        const float* wc = wmat + (size_t)col * M;
#pragma unroll
        for (int m = 0; m < 4; ++m) {
            int row0 = rowBase + wm * 64 + m * 16 + lg * 4;
#pragma unroll
            for (int i = 0; i < 4; ++i) {
                float v = acc[m][n][i] + bv;
                psum[m][i] += v * wc[row0 + i];
            }
        }
    }
#pragma unroll
    for (int m = 0; m < 4; ++m)
#pragma unroll
        for (int i = 0; i < 4; ++i) {
#pragma unroll
            for (int mask = 1; mask < 16; mask <<= 1)
                psum[m][i] += __shfl_xor(psum[m][i], mask);
        }
    if (lr == 0) {
#pragma unroll
        for (int m = 0; m < 4; ++m) {
            int row0 = rowBase + wm * 64 + m * 16 + lg * 4;
#pragma unroll
            for (int i = 0; i < 4; ++i)
                atomicAdd(&out[row0 + i], psum[m][i]);
        }
    }
}

// ---------- launch ----------
extern "C" void kernel_launch(void* const* d_in, const int* in_sizes, int n_in,
                              void* d_out, int out_size, void* d_ws, size_t ws_size,
                              hipStream_t stream) {
    const float* features = (const float*)d_in[0];  // [4096,1024]
    const float* W1 = (const float*)d_in[1];        // [1024,2048]
    const float* b1 = (const float*)d_in[2];
    const float* W2 = (const float*)d_in[3];        // [2048,2048]
    const float* b2 = (const float*)d_in[4];
    const float* W3 = (const float*)d_in[5];        // [2048,1024]
    const float* b3 = (const float*)d_in[6];
    const float* Wh = (const float*)d_in[7];        // [1024,512]
    const float* bh = (const float*)d_in[8];
    const float* w  = (const float*)d_in[9];        // [512,4096]
    float* out = (float*)d_out;

    const int N = 4096, D_in = 1024, H1 = 2048, H2 = 2048, H3 = 1024, D_out = 512;

    size_t off = 0;
    auto alloc = [&](size_t bytes) {
        void* p = (char*)d_ws + off;
        off += (bytes + 255) & ~(size_t)255;
        return p;
    };
    u16* featB = (u16*)alloc((size_t)N * D_in * 2);      // 8MB; reused as h3
    u16* W1T   = (u16*)alloc((size_t)H1 * D_in * 2);     // 4MB
    u16* W2T   = (u16*)alloc((size_t)H2 * H1 * 2);       // 8MB
    u16* W3T   = (u16*)alloc((size_t)H3 * H2 * 2);       // 4MB
    u16* WhT   = (u16*)alloc((size_t)D_out * H3 * 2);    // 1MB
    u16* h1    = (u16*)alloc((size_t)N * H1 * 2);        // 16MB
    u16* h2    = (u16*)alloc((size_t)N * H2 * 2);        // 16MB
    u16* h3    = featB;                                  // alias (GEMM1 done with featB)

    // out accumulated via atomics -> zero it
    hipMemsetAsync(out, 0, (size_t)N * sizeof(float), stream);

    // 1. merged prep (cvt + 4 transposes): 2048+2048+4096+2048+512 blocks
    prep_kernel<<<10752, 256, 0, stream>>>(features, featB, W1, W1T, W2, W2T,
                                           W3, W3T, Wh, WhT);

    // 2. GEMM chain
    gemm_bt<1><<<dim3(H1 / 128, N / 128), 256, 0, stream>>>(featB, W1T, b1, h1, N, H1, D_in);
    gemm_bt<1><<<dim3(H2 / 128, N / 128), 256, 0, stream>>>(h1, W2T, b2, h2, N, H2, H1);
    gemm_bt<0><<<dim3(H3 / 128, N / 128), 256, 0, stream>>>(h2, W3T, b3, h3, N, H3, H2);

    // 3. fused GEMM4 + row-dot
    gemm_dot<<<dim3(D_out / 128, N / 128), 256, 0, stream>>>(h3, WhT, bh, w, out, N, D_out, H3);
}